// Round 6
// baseline (410.239 us; speedup 1.0000x reference)
//
#include <hip/hip_runtime.h>
#include <math.h>

#define TWO_PI_F 6.283185307179586f

constexpr int B = 8;

// Workspace layout (floats)
constexpr size_t OFF_DW = 0;        // 2048
constexpr size_t OFF_DP = 2048;     // 4096
constexpr size_t OFF_DC = 6144;     // 6144
constexpr size_t OFF_CW = 12288;    // 163840
constexpr size_t OFF_CP = 176128;   // 327680
constexpr size_t OFF_CC = 503808;   // 491520
constexpr size_t OFF_S  = 995328;   // 163840 (split 0 of s)
constexpr size_t OFF_T  = 1159168;  // tail scalars (~625)
constexpr size_t OFF_SP = 1160192;  // split partials 1..3 (<= 307200 floats)

typedef short s16x8 __attribute__((ext_vector_type(8)));
typedef float f32x4 __attribute__((ext_vector_type(4)));

__device__ __forceinline__ short f2bf(float x) {          // RNE fp32->bf16
    unsigned u = __float_as_uint(x);
    return (short)((u + 0x7fffu + ((u >> 16) & 1u)) >> 16);
}
__device__ __forceinline__ float bf2f(short s) {
    return __uint_as_float(((unsigned)(unsigned short)s) << 16);
}

// ======== barrier-free per-wave conv + MFMA eval (split-j partials) =========
// One slice (b,co,sup,sp) per WAVE. Wave owns ROWS=128 i-rows (NF=8 A-frags
// in regs), iterates its j-range in 64-j chunks: each lane convs ONE j and
// writes its packed C-row to the wave's private LDS region; MFMA reads it
// back. Correctness relies on per-wave in-order LDS execution (no barriers;
// sched_barrier(0) pins compiler order). X-staging LDS is reused as the
// C-buffer (afr already in regs). sfac/sscl live in unused row-slot bytes.
template <int CO, int CI, int ND, bool L0, int JS>
__global__ __launch_bounds__(256, 4) void eval_wave_kernel(
        const float* __restrict__ dw, const float* __restrict__ dp,
        const float* __restrict__ dc,
        const float* __restrict__ kw, const float* __restrict__ kp,
        const float* __restrict__ kc,
        const float* __restrict__ trp, const float* __restrict__ aip,
        float* __restrict__ cw, float* __restrict__ cp, float* __restrict__ cc,
        float* __restrict__ sb0, float* __restrict__ sbP, int* __restrict__ cnt) {
    constexpr int N    = CI * ND * 5;
    constexpr int ROWS = 128;
    constexpr int NSUP = N / ROWS;
    constexpr int NJ   = N / JS;        // j per split
    constexpr int NCH  = NJ / 64;
    constexpr int NF   = ROWS / 16;     // 8 A-frags per wave
    constexpr int RS   = 40;            // row stride (shorts, 80B)
    constexpr size_t SST = (size_t)B * CO * N;

    __shared__ __align__(16) short lds[4 * ROWS * RS];

    int t = threadIdx.x;
    int wave = t >> 6, lane = t & 63;
    int col = lane & 15, quad = lane >> 4;
    short* reg = &lds[wave * ROWS * RS];

    int slice = blockIdx.x * 4 + wave;
    int sp  = slice % JS;
    int sup = (slice / JS) % NSUP;
    int bl  = slice / (JS * NSUP);
    int b = bl / CO, co = bl % CO;
    size_t base = (size_t)bl * N;
    const float NHL2E = -0.72134752044448f;   // -0.5*log2(e)

    if (L0 && blockIdx.x == 0 && t == 0) *cnt = 0;

    // ---- phase A: per-channel norm factors (wave-local, no barriers) ----
    float f_s = 0.f, is_s = 0.f;
    if (L0) {
        int i0 = b * 128 + lane, i1 = i0 + 64;
        float w0a = dw[i0], w0b = dw[i1];
        float a00 = dc[4 * i0], a01 = dc[4 * i0 + 1], a11 = dc[4 * i0 + 3];
        float b00 = dc[4 * i1], b01 = dc[4 * i1 + 1], b11 = dc[4 * i1 + 3];
        float tr = 0.5f * (a00 + a11) + 0.5f * (b00 + b11);
#pragma unroll
        for (int off = 32; off > 0; off >>= 1) tr += __shfl_xor(tr, off, 64);
        float f = rsqrtf(tr / 128.f + 1e-8f);
        float f2 = f * f, f4 = f2 * f2;
        float da = (a00 * a11 - a01 * a01) * f4;
        float db = (b00 * b11 - b01 * b01) * f4;
        float s = fabsf(w0a * TWO_PI_F * sqrtf(fmaxf(da, 1e-12f)))
                + fabsf(w0b * TWO_PI_F * sqrtf(fmaxf(db, 1e-12f)));
#pragma unroll
        for (int off = 32; off > 0; off >>= 1) s += __shfl_xor(s, off, 64);
        f_s = f; is_s = 1.0f / (s / 128.f + 1e-6f);
    } else {
        if (lane < CI) {
            float str = 0.f, sai = 0.f;
            for (int bb = 0; bb < B; ++bb) { str += trp[lane * B + bb]; sai += aip[lane * B + bb]; }
            float M = (float)(B * ND);
            float f = rsqrtf(str / M + 1e-8f);
            // stash in unused slot bytes of rows 64..64+CI (never touched by X/C packs)
            *(float*)&reg[(64 + lane) * RS + 34] = f;
            *(float*)&reg[(64 + lane) * RS + 36] = 1.0f / (f * f * sai / M + 1e-6f);
        }
        __builtin_amdgcn_sched_barrier(0);
    }

    // ---- stage ROWS X-rows into this wave's LDS region ----
    for (int r = lane; r < ROWS; r += 64) {
        int i = sup * ROWS + r;
        int dl = i / 5, nk = i % 5;
        int ci = dl / ND;
        int di = (b * CI + ci) * ND + (dl % ND);
        int ki = (co * CI + ci) * 5 + nk;
        float f = L0 ? f_s : *(const float*)&reg[(64 + ci) * RS + 34];
        float p0 = f * dp[2 * di] + kp[2 * ki];
        float p1 = f * dp[2 * di + 1] + kp[2 * ki + 1];
        float v[6] = {p0 * p0, p0 * p1, p1 * p1, p0, p1, 1.0f};
        short h[6], l[6];
#pragma unroll
        for (int q = 0; q < 6; ++q) {
            h[q] = f2bf(v[q]);
            l[q] = f2bf(v[q] - bf2f(h[q]));
        }
        s16x8 r0, r1, r2, r3;
        r0[0]=h[0]; r0[1]=h[1]; r0[2]=h[2]; r0[3]=h[3]; r0[4]=h[4]; r0[5]=h[5]; r0[6]=l[0]; r0[7]=l[1];
        r1[0]=l[2]; r1[1]=l[3]; r1[2]=l[4]; r1[3]=l[5]; r1[4]=h[0]; r1[5]=h[1]; r1[6]=h[2]; r1[7]=h[3];
        r2[0]=h[4]; r2[1]=h[5]; r2[2]=l[0]; r2[3]=l[1]; r2[4]=l[2]; r2[5]=l[3]; r2[6]=l[4]; r2[7]=l[5];
        r3 = (s16x8){0,0,0,0,0,0,0,0};
        s16x8* row = (s16x8*)&reg[r * RS];
        row[0] = r0; row[1] = r1; row[2] = r2; row[3] = r3;
    }
    __builtin_amdgcn_sched_barrier(0);

    s16x8 afr[NF];
    f32x4 sacc[NF];
#pragma unroll
    for (int n = 0; n < NF; ++n) {
        afr[n] = *(const s16x8*)&reg[((n * 16 + col) * RS) + quad * 8];
        sacc[n] = (f32x4){0.f, 0.f, 0.f, 0.f};
    }
    __builtin_amdgcn_sched_barrier(0);

    // ---- j chunks: lane-conv into rows 0..63 (slots 24..31 stay 0 from X),
    //      then MFMA+exp2. No barriers: per-wave in-order LDS. ----
    for (int ch = 0; ch < NCH; ++ch) {
        {
            int jg = sp * NJ + ch * 64 + lane;
            int dl = jg / 5, nk = jg % 5;
            int ci = dl / ND;
            int di = (b * CI + ci) * ND + (dl % ND);
            int ki = (co * CI + ci) * 5 + nk;
            float f, iscl;
            if (L0) { f = f_s; iscl = is_s; }
            else {
                f    = *(const float*)&reg[(64 + ci) * RS + 34];
                iscl = *(const float*)&reg[(64 + ci) * RS + 36];
            }
            float f2 = f * f;
            float wd = dw[di] * iscl;
            float pd0 = f * dp[2 * di], pd1 = f * dp[2 * di + 1];
            float d00, d01, d11;
            if (L0) { d00 = f2 * dc[4 * di]; d01 = f2 * dc[4 * di + 1]; d11 = f2 * dc[4 * di + 3]; }
            else    { d00 = f2 * dc[3 * di]; d01 = f2 * dc[3 * di + 1]; d11 = f2 * dc[3 * di + 2]; }
            float wk = kw[ki], pk0 = kp[2 * ki], pk1 = kp[2 * ki + 1];
            float k00 = kc[4 * ki], k01 = kc[4 * ki + 1], k11 = kc[4 * ki + 3];
            float s00 = d00 + k00, s01 = d01 + k01, s11 = d11 + k11;
            float det_d = d00 * d11 - d01 * d01;
            float det_k = k00 * k11 - k01 * k01;
            float det_s = s00 * s11 - s01 * s01;
            float rds = 1.0f / fmaxf(det_s, 1e-12f);
            float amp = TWO_PI_F * sqrtf(fmaxf(det_d * det_k * rds, 1e-20f));
            float w = wd * wk * amp;
            float q0 = pd0 + pk0, q1 = pd1 + pk1;
            if (sup == 0) {
                size_t o = base + jg;
                cw[o] = w; cp[2 * o] = q0; cp[2 * o + 1] = q1;
                cc[3 * o] = s00; cc[3 * o + 1] = s01; cc[3 * o + 2] = s11;
            }
            float dinv = NHL2E * rds;
            float A00 = s11 * dinv, A01h = -2.f * s01 * dinv, A11 = s00 * dinv;
            float u0 = -(2.f * A00 * q0 + A01h * q1);
            float u1 = -(A01h * q0 + 2.f * A11 * q1);
            float cj = (A00 * q0 + A01h * q1) * q0 + A11 * q1 * q1;
            float v[6] = {A00, A01h, A11, u0, u1, cj};
            short h[6], l[6];
#pragma unroll
            for (int q = 0; q < 6; ++q) {
                h[q] = f2bf(v[q]);
                l[q] = f2bf(v[q] - bf2f(h[q]));
            }
            s16x8 r0, r1, r2;
            r0[0]=h[0]; r0[1]=h[1]; r0[2]=h[2]; r0[3]=h[3]; r0[4]=h[4]; r0[5]=h[5]; r0[6]=h[0]; r0[7]=h[1];
            r1[0]=h[2]; r1[1]=h[3]; r1[2]=h[4]; r1[3]=h[5]; r1[4]=l[0]; r1[5]=l[1]; r1[6]=l[2]; r1[7]=l[3];
            r2[0]=l[4]; r2[1]=l[5]; r2[2]=l[0]; r2[3]=l[1]; r2[4]=l[2]; r2[5]=l[3]; r2[6]=l[4]; r2[7]=l[5];
            s16x8* row = (s16x8*)&reg[lane * RS];
            row[0] = r0; row[1] = r1; row[2] = r2;
            *(float*)&reg[lane * RS + 32] = w;
        }
        __builtin_amdgcn_sched_barrier(0);

#pragma unroll
        for (int jt = 0; jt < 4; ++jt) {
            s16x8 bfr = *(const s16x8*)&reg[((jt * 16 + col) * RS) + quad * 8];
            float wv = *(const float*)&reg[(jt * 16 + col) * RS + 32];
#pragma unroll
            for (int n = 0; n < NF; ++n) {
                f32x4 g = __builtin_amdgcn_mfma_f32_16x16x32_bf16(
                    afr[n], bfr, (f32x4){0.f, 0.f, 0.f, 0.f}, 0, 0, 0);
#pragma unroll
                for (int r = 0; r < 4; ++r)
                    sacc[n][r] = fmaf(wv, __builtin_amdgcn_exp2f(g[r]), sacc[n][r]);
            }
        }
        __builtin_amdgcn_sched_barrier(0);
    }

    // ---- reduce over 16 cols (j) and store partial s for this split ----
    float* dst = (sp == 0) ? sb0 : sbP + (size_t)(sp - 1) * SST;
#pragma unroll
    for (int n = 0; n < NF; ++n) {
#pragma unroll
        for (int r = 0; r < 4; ++r) {
            float v = sacc[n][r];
            v += __shfl_xor(v, 1, 64);
            v += __shfl_xor(v, 2, 64);
            v += __shfl_xor(v, 4, 64);
            v += __shfl_xor(v, 8, 64);
            sacc[n][r] = v;
        }
        if (col == 0) {
            int ig = sup * ROWS + n * 16 + quad * 4;
            float4 st = make_float4(sacc[n][0], sacc[n][1], sacc[n][2], sacc[n][3]);
            *(float4*)&dst[base + ig] = st;
        }
    }
}

// ===== topk: relu-finish (split-sum) + RADIX-SELECT on packed u64 key ======
__global__ __launch_bounds__(256) void topk_kernel(
        const float* __restrict__ sb0, const float* __restrict__ sbP,
        const float* __restrict__ cw,
        const float* __restrict__ cp, const float* __restrict__ cc,
        float* __restrict__ dw, float* __restrict__ dp, float* __restrict__ dc,
        float* __restrict__ trp, float* __restrict__ aip,
        int N, int K, int L, int js, long sst) {
    __shared__ unsigned long long skey[1280];
    __shared__ float swn[1280];
    __shared__ int hist[256];
    __shared__ int suff[256];
    __shared__ int sel[32];
    __shared__ int scnt;
    __shared__ unsigned long long sprefix;
    __shared__ int sneed, sdone;

    int blv = blockIdx.x;
    int b = blv / L, l = blv % L;
    size_t base = (size_t)blv * N;
    int t = threadIdx.x;

    for (int j = t; j < N; j += 256) {
        float s = sb0[base + j];
        for (int sp = 1; sp < js; ++sp) s += sbP[(size_t)(sp - 1) * sst + base + j];
        float denom = (fabsf(s) > 1e-6f) ? s : 1e-6f;
        float wn = cw[base + j] * (fmaxf(s, 0.f) / denom);
        swn[j] = wn;
        float c00 = cc[3 * (base + j)], c01 = cc[3 * (base + j) + 1],
              c11 = cc[3 * (base + j) + 2];
        float det = c00 * c11 - c01 * c01;
        float sc = fabsf(wn) * sqrtf(fmaxf(det, 1e-12f));
        unsigned int ub = __float_as_uint(sc) | 0x80000000u;
        skey[j] = ((unsigned long long)ub << 32) | (unsigned int)(~j);
    }
    if (t == 0) { scnt = 0; }
    __syncthreads();

    unsigned long long prefix = 0;
    int need = K;
    unsigned long long Wlo = 0;
    for (int lvl = 7; lvl >= 0; --lvl) {
        hist[t] = 0;
        __syncthreads();
        int sh = lvl * 8;
        unsigned long long pmask = (lvl == 7) ? 0ull : (~0ull << (sh + 8));
        for (int j = t; j < N; j += 256) {
            unsigned long long k_ = skey[j];
            if ((k_ & pmask) == prefix)
                atomicAdd(&hist[(int)((k_ >> sh) & 255)], 1);
        }
        __syncthreads();
        suff[t] = hist[t];
        __syncthreads();
        for (int off = 1; off < 256; off <<= 1) {
            int add = (t + off < 256) ? suff[t + off] : 0;
            __syncthreads();
            suff[t] += add;
            __syncthreads();
        }
        int snx = (t < 255) ? suff[t + 1] : 0;
        if (suff[t] >= need && snx < need) {
            sprefix = prefix | ((unsigned long long)t << sh);
            sneed = need - snx;
            sdone = (suff[t] == need);
        }
        __syncthreads();
        prefix = sprefix;
        need = sneed;
        if (sdone) { Wlo = prefix; break; }
        __syncthreads();
    }

    for (int j = t; j < N; j += 256) {
        if (skey[j] >= Wlo) {
            int slot = atomicAdd(&scnt, 1);
            if (slot < 32) sel[slot] = j;
        }
    }
    __syncthreads();

    float tr_c = 0.f, ai_c = 0.f;
    if (t < K) {
        int idx = sel[t];
        size_t j = base + idx;
        int o = blv * K + t;
        float wn = swn[idx];
        float c00 = cc[3 * j], c01 = cc[3 * j + 1], c11 = cc[3 * j + 2];
        dw[o] = wn;
        dp[2 * o] = cp[2 * j]; dp[2 * o + 1] = cp[2 * j + 1];
        dc[3 * o] = c00; dc[3 * o + 1] = c01; dc[3 * o + 2] = c11;
        tr_c = 0.5f * (c00 + c11);
        float det = c00 * c11 - c01 * c01;
        ai_c = fabsf(wn * TWO_PI_F * sqrtf(fmaxf(det, 1e-12f)));
    }
    if (t < 64) {
        for (int off = 32; off > 0; off >>= 1) {
            tr_c += __shfl_down(tr_c, off, 64);
            ai_c += __shfl_down(ai_c, off, 64);
        }
        if (t == 0) { trp[l * B + b] = tr_c; aip[l * B + b] = ai_c; }
    }
}

// ==== final: per-(b,co) partials; last block does norm + BN + log_softmax ===
__global__ __launch_bounds__(256) void final_kernel(
        const float* __restrict__ sb0, const float* __restrict__ sbP,
        const float* __restrict__ cw, const float* __restrict__ cc,
        float* __restrict__ tbuf, float* __restrict__ ubuf, float* __restrict__ abuf,
        int* __restrict__ cnt, float* __restrict__ out,
        int L, int N, int js, long sst) {
    int blv = blockIdx.x;
    size_t base = (size_t)blv * N;
    int t = threadIdx.x;
    __shared__ float r1[256], r2[256], r3[256];

    float tsum = 0.f, usum = 0.f, asum = 0.f;
    for (int n = t; n < N; n += 256) {
        size_t o = base + n;
        float c00 = cc[3 * o], c01 = cc[3 * o + 1], c11 = cc[3 * o + 2];
        tsum += 0.5f * (c00 + c11);
        float s = sb0[o];
        for (int sp = 1; sp < js; ++sp) s += sbP[(size_t)(sp - 1) * sst + o];
        float denom = (fabsf(s) > 1e-6f) ? s : 1e-6f;
        float wn = cw[o] * (fmaxf(s, 0.f) / denom);
        float det = fmaxf(c00 * c11 - c01 * c01, 1e-30f);
        float integ = wn * TWO_PI_F * sqrtf(det);
        usum += integ;
        asum += fabsf(integ);
    }
    r1[t] = tsum; r2[t] = usum; r3[t] = asum;
    __syncthreads();
    for (int s = 128; s > 0; s >>= 1) {
        if (t < s) { r1[t] += r1[t + s]; r2[t] += r2[t + s]; r3[t] += r3[t + s]; }
        __syncthreads();
    }
    __shared__ int lastf;
    if (t == 0) {
        tbuf[blv] = r1[0]; ubuf[blv] = r2[0]; abuf[blv] = r3[0];
        __threadfence();
        lastf = (atomicAdd(cnt, 1) == (int)gridDim.x - 1);
    }
    __syncthreads();
    if (!lastf) return;
    __threadfence();

    __shared__ float xs[80];
    __shared__ float xn[80];
    if (t < L) {
        float tr = 0.f, a = 0.f;
        for (int bb = 0; bb < B; ++bb) { tr += tbuf[bb * L + t]; a += abuf[bb * L + t]; }
        float m = tr / (float)(B * N);
        float f = rsqrtf(m + 1e-8f);
        float f2 = f * f;
        float scale = f2 * a / (float)(B * N) + 1e-6f;
        for (int bb = 0; bb < B; ++bb) xs[bb * L + t] = f2 * ubuf[bb * L + t] / scale;
    }
    __syncthreads();
    if (t < L) {
        float mu = 0.f;
        for (int bb = 0; bb < B; ++bb) mu += xs[bb * L + t];
        mu *= 0.125f;
        float var = 0.f;
        for (int bb = 0; bb < B; ++bb) { float d = xs[bb * L + t] - mu; var += d * d; }
        var *= 0.125f;
        float inv = rsqrtf(var + 1e-5f);
        for (int bb = 0; bb < B; ++bb) xn[bb * L + t] = (xs[bb * L + t] - mu) * inv;
    }
    __syncthreads();
    if (t < B) {
        float mx = -INFINITY;
        for (int c = 0; c < L; ++c) mx = fmaxf(mx, xn[t * L + c]);
        float se = 0.f;
        for (int c = 0; c < L; ++c) se += expf(xn[t * L + c] - mx);
        float lse = mx + logf(se);
        for (int c = 0; c < L; ++c) out[t * L + c] = xn[t * L + c] - lse;
    }
}

extern "C" void kernel_launch(void* const* d_in, const int* in_sizes, int n_in,
                              void* d_out, int out_size, void* d_ws, size_t ws_size,
                              hipStream_t stream) {
    const float* in_w = (const float*)d_in[0];
    const float* in_p = (const float*)d_in[1];
    const float* in_c = (const float*)d_in[2];
    const float* kw[3] = {(const float*)d_in[3], (const float*)d_in[6], (const float*)d_in[9]};
    const float* kp[3] = {(const float*)d_in[4], (const float*)d_in[7], (const float*)d_in[10]};
    const float* kc[3] = {(const float*)d_in[5], (const float*)d_in[8], (const float*)d_in[11]};

    float* ws  = (float*)d_ws;
    float* dw  = ws + OFF_DW;
    float* dp  = ws + OFF_DP;
    float* dc  = ws + OFF_DC;
    float* cw  = ws + OFF_CW;
    float* cp  = ws + OFF_CP;
    float* cc  = ws + OFF_CC;
    float* sb  = ws + OFF_S;
    float* sbP = ws + OFF_SP;
    float* out = (float*)d_out;

    float* tail = ws + OFF_T;
    float* trp0 = tail;          // 64
    float* aip0 = tail + 64;     // 64
    float* trp1 = tail + 128;    // 128
    float* aip1 = tail + 256;    // 128
    float* tbuf = tail + 384;    // 80
    float* ubuf = tail + 464;    // 80
    float* abuf = tail + 544;    // 80
    int*   cnt  = (int*)(tail + 624);

    // layer 0: Co=8, Ci=1, Nd=128, N=640, NSUP=5, JS=2 -> 640 waves / 160 blocks
    eval_wave_kernel<8, 1, 128, true, 2><<<160, 256, 0, stream>>>(
        in_w, in_p, in_c, kw[0], kp[0], kc[0], nullptr, nullptr,
        cw, cp, cc, sb, sbP, cnt);
    topk_kernel<<<64, 256, 0, stream>>>(sb, sbP, cw, cp, cc, dw, dp, dc,
                                        trp0, aip0, 640, 32, 8, 2, 40960L);
    // layer 1: Co=16, Ci=8, Nd=32, N=1280, NSUP=10, JS=2 -> 2560 waves / 640 blocks
    eval_wave_kernel<16, 8, 32, false, 2><<<640, 256, 0, stream>>>(
        dw, dp, dc, kw[1], kp[1], kc[1], trp0, aip0, cw, cp, cc, sb, sbP, cnt);
    topk_kernel<<<128, 256, 0, stream>>>(sb, sbP, cw, cp, cc, dw, dp, dc,
                                         trp1, aip1, 1280, 16, 16, 2, 163840L);
    // layer 2: Co=10, Ci=16, Nd=16, N=1280, NSUP=10, JS=4 -> 3200 waves / 800 blocks
    eval_wave_kernel<10, 16, 16, false, 4><<<800, 256, 0, stream>>>(
        dw, dp, dc, kw[2], kp[2], kc[2], trp1, aip1, cw, cp, cc, sb, sbP, cnt);
    final_kernel<<<80, 256, 0, stream>>>(sb, sbP, cw, cc, tbuf, ubuf, abuf,
                                         cnt, out, 10, 1280, 4, 102400L);
}

// Round 7
// 187.956 us; speedup vs baseline: 2.1826x; 2.1826x over previous
//
#include <hip/hip_runtime.h>
#include <math.h>

#define TWO_PI_F 6.283185307179586f

constexpr int B = 8;

// Workspace layout (floats)
constexpr size_t OFF_DW = 0;        // 2048
constexpr size_t OFF_DP = 2048;     // 4096
constexpr size_t OFF_DC = 6144;     // 6144
constexpr size_t OFF_CW = 12288;    // 163840
constexpr size_t OFF_CP = 176128;   // 327680
constexpr size_t OFF_CC = 503808;   // 491520
constexpr size_t OFF_S  = 995328;   // 163840 (direct s, no partials)
constexpr size_t OFF_T  = 1159168;  // tail scalars

typedef short s16x8 __attribute__((ext_vector_type(8)));
typedef float f32x4 __attribute__((ext_vector_type(4)));

__device__ __forceinline__ short f2bf(float x) {          // RNE fp32->bf16
    unsigned u = __float_as_uint(x);
    return (short)((u + 0x7fffu + ((u >> 16) & 1u)) >> 16);
}
__device__ __forceinline__ float bf2f(short s) {
    return __uint_as_float(((unsigned)(unsigned short)s) << 16);
}

// ============ fused conv + MFMA eval, loop-swapped (direct s) ===============
// R5 structure + sX/sC ALIASED into one buffer sU: the X-staging region is
// dead after afr is loaded to registers, so the conv chunks reuse it. LDS
// drops 40.4->30.4 KB -> 5 blocks/CU resident (was 3) so the whole L1 grid
// is co-resident and conv/barrier phases hide under other blocks' MFMA+exp.
template <int CO, int CI, int ND, bool L0, int ROWS, int JCH>
__global__ __launch_bounds__(256) void eval_mfma_kernel(
        const float* __restrict__ dw, const float* __restrict__ dp,
        const float* __restrict__ dc,
        const float* __restrict__ kw, const float* __restrict__ kp,
        const float* __restrict__ kc,
        const float* __restrict__ trp, const float* __restrict__ aip,
        float* __restrict__ cw, float* __restrict__ cp, float* __restrict__ cc,
        float* __restrict__ sbuf, int* __restrict__ cnt) {
    constexpr int N    = CI * ND * 5;
    constexpr int NSUP = N / ROWS;
    constexpr int NCH  = N / JCH;
    constexpr int NF   = ROWS / 64;     // A fragments per wave
    constexpr int JT   = JCH / 16;      // B fragments per chunk
    constexpr int FAC  = (CI < 2) ? 2 : CI;
    constexpr int LDP  = 40;            // padded LDS row stride (shorts, 80B)
    constexpr int NDAT = CI * ND;       // data rows per (b)
    constexpr int NKER = CI * 5;        // kernel rows per (co)
    static_assert(JCH >= ROWS, "sU alias requires JCH >= ROWS");

    __shared__ __align__(16) short sU[JCH * LDP];   // X rows, then C chunks
    __shared__ float sw_[JCH];
    __shared__ float sD[NDAT * 7];
    __shared__ float sK[NKER * 7];
    __shared__ float sfac[FAC], sscl[FAC];   // sscl holds RECIPROCAL scale
    __shared__ float red[128];

    int blk = blockIdx.x;
    int sup = blk % NSUP;
    int bl  = blk / NSUP;                 // b*CO + co
    int b = bl / CO, co = bl % CO;
    int t = threadIdx.x;
    size_t base = (size_t)bl * N;
    const float NHL2E = -0.72134752044448f;   // -0.5*log2(e)

    if (L0 && blk == 0 && t == 0) *cnt = 0;

    // ---- phase A: per-channel norm factors ----
    if (L0) {
        float w0 = 0.f, c00 = 0.f, c01 = 0.f, c11 = 0.f;
        if (t < 128) {
            int idx = b * 128 + t;
            w0 = dw[idx];
            c00 = dc[4 * idx]; c01 = dc[4 * idx + 1]; c11 = dc[4 * idx + 3];
        }
        if (t < 128) red[t] = 0.5f * (c00 + c11);
        __syncthreads();
        for (int s = 64; s > 0; s >>= 1) {
            if (t < s) red[t] += red[t + s];
            __syncthreads();
        }
        float f = rsqrtf(red[0] / 128.f + 1e-8f);
        __syncthreads();
        float f2 = f * f;
        float det = (c00 * c11 - c01 * c01) * f2 * f2;
        if (t < 128) red[t] = fabsf(w0 * TWO_PI_F * sqrtf(fmaxf(det, 1e-12f)));
        __syncthreads();
        for (int s = 64; s > 0; s >>= 1) {
            if (t < s) red[t] += red[t + s];
            __syncthreads();
        }
        if (t == 0) { sfac[0] = f; sscl[0] = 1.0f / (red[0] / 128.f + 1e-6f); }
    } else {
        if (t < CI) {
            float str = 0.f, sai = 0.f;
            for (int bb = 0; bb < B; ++bb) { str += trp[t * B + bb]; sai += aip[t * B + bb]; }
            float M = (float)(B * ND);
            float f = rsqrtf(str / M + 1e-8f);
            sfac[t] = f; sscl[t] = 1.0f / (f * f * sai / M + 1e-6f);
        }
    }
    __syncthreads();

    // ---- phase B0: stage normalized data + kernel rows into LDS ----
    for (int r = t; r < NDAT; r += 256) {
        int ci = r / ND;
        int di = (b * CI + ci) * ND + (r % ND);
        float f = sfac[ci], iscl = sscl[ci], f2 = f * f;
        float wdn = dw[di] * iscl;
        float p0 = f * dp[2 * di], p1 = f * dp[2 * di + 1];
        float d00, d01, d11;
        if (L0) { d00 = f2 * dc[4 * di]; d01 = f2 * dc[4 * di + 1]; d11 = f2 * dc[4 * di + 3]; }
        else    { d00 = f2 * dc[3 * di]; d01 = f2 * dc[3 * di + 1]; d11 = f2 * dc[3 * di + 2]; }
        float* row = &sD[r * 7];
        row[0] = wdn; row[1] = p0; row[2] = p1;
        row[3] = d00; row[4] = d01; row[5] = d11;
        row[6] = d00 * d11 - d01 * d01;
    }
    for (int r = t; r < NKER; r += 256) {
        int ki = co * NKER + r;
        float k00 = kc[4 * ki], k01 = kc[4 * ki + 1], k11 = kc[4 * ki + 3];
        float* row = &sK[r * 7];
        row[0] = kw[ki]; row[1] = kp[2 * ki]; row[2] = kp[2 * ki + 1];
        row[3] = k00; row[4] = k01; row[5] = k11;
        row[6] = k00 * k11 - k01 * k01;
    }
    __syncthreads();

    // ---- phase B1: stage ROWS X-rows (positions) from sD/sK into sU ----
    for (int r = t; r < ROWS; r += 256) {
        int i = sup * ROWS + r;
        int dl = i / 5, nk = i % 5;
        int kl = (dl / ND) * 5 + nk;
        float p0 = sD[dl * 7 + 1] + sK[kl * 7 + 1];
        float p1 = sD[dl * 7 + 2] + sK[kl * 7 + 2];
        float v[6] = {p0 * p0, p0 * p1, p1 * p1, p0, p1, 1.0f};
        short h[6], l[6];
#pragma unroll
        for (int q = 0; q < 6; ++q) {
            h[q] = f2bf(v[q]);
            l[q] = f2bf(v[q] - bf2f(h[q]));
        }
        // slots: [h0..5, l0..5, h0..5, l0..5, 0 x8]
        s16x8 r0, r1, r2, r3;
        r0[0]=h[0]; r0[1]=h[1]; r0[2]=h[2]; r0[3]=h[3]; r0[4]=h[4]; r0[5]=h[5]; r0[6]=l[0]; r0[7]=l[1];
        r1[0]=l[2]; r1[1]=l[3]; r1[2]=l[4]; r1[3]=l[5]; r1[4]=h[0]; r1[5]=h[1]; r1[6]=h[2]; r1[7]=h[3];
        r2[0]=h[4]; r2[1]=h[5]; r2[2]=l[0]; r2[3]=l[1]; r2[4]=l[2]; r2[5]=l[3]; r2[6]=l[4]; r2[7]=l[5];
        r3 = (s16x8){0,0,0,0,0,0,0,0};
        s16x8* row = (s16x8*)&sU[r * LDP];
        row[0] = r0; row[1] = r1; row[2] = r2; row[3] = r3;
    }
    __syncthreads();

    int lane = t & 63, wave = t >> 6;
    int col = lane & 15, quad = lane >> 4;
    s16x8 afr[NF];
    f32x4 sacc[NF];
#pragma unroll
    for (int n = 0; n < NF; ++n) {
        int it = wave * NF + n;
        afr[n] = *(const s16x8*)&sU[((it * 16 + col) * LDP) + quad * 8];
        sacc[n] = (f32x4){0.f, 0.f, 0.f, 0.f};
    }

    // ---- j chunks: conv (pure LDS) + pack into sU, then MFMA+exp2 ----
    for (int ch = 0; ch < NCH; ++ch) {
        __syncthreads();           // afr in regs; protect sU from prior reads
        if (t < JCH) {
            int n = ch * JCH + t;
            int dl = n / 5, nk = n % 5;
            int kl = (dl / ND) * 5 + nk;
            const float* dR = &sD[dl * 7];
            const float* kR = &sK[kl * 7];
            float wdn = dR[0], pd0 = dR[1], pd1 = dR[2];
            float d00 = dR[3], d01 = dR[4], d11 = dR[5], det_d = dR[6];
            float wk = kR[0], pk0 = kR[1], pk1 = kR[2];
            float k00 = kR[3], k01 = kR[4], k11 = kR[5], det_k = kR[6];
            float s00 = d00 + k00, s01 = d01 + k01, s11 = d11 + k11;
            float det_s = s00 * s11 - s01 * s01;
            float rds = 1.0f / fmaxf(det_s, 1e-12f);
            float amp = TWO_PI_F * sqrtf(fmaxf(det_d * det_k * rds, 1e-20f));
            float w = wdn * wk * amp;
            float q0 = pd0 + pk0, q1 = pd1 + pk1;
            if (sup == 0) {
                size_t o = base + n;
                cw[o] = w; cp[2 * o] = q0; cp[2 * o + 1] = q1;
                cc[3 * o] = s00; cc[3 * o + 1] = s01; cc[3 * o + 2] = s11;
            }
            float dinv = NHL2E * rds;
            float A00 = s11 * dinv, A01h = -2.f * s01 * dinv, A11 = s00 * dinv;
            float u0 = -(2.f * A00 * q0 + A01h * q1);
            float u1 = -(A01h * q0 + 2.f * A11 * q1);
            float cj = (A00 * q0 + A01h * q1) * q0 + A11 * q1 * q1;
            float v[6] = {A00, A01h, A11, u0, u1, cj};
            short h[6], l[6];
#pragma unroll
            for (int q = 0; q < 6; ++q) {
                h[q] = f2bf(v[q]);
                l[q] = f2bf(v[q] - bf2f(h[q]));
            }
            // slots: [ch0..5, ch0..5, cl0..5, cl0..5, 0 x8]
            s16x8 r0, r1, r2, r3;
            r0[0]=h[0]; r0[1]=h[1]; r0[2]=h[2]; r0[3]=h[3]; r0[4]=h[4]; r0[5]=h[5]; r0[6]=h[0]; r0[7]=h[1];
            r1[0]=h[2]; r1[1]=h[3]; r1[2]=h[4]; r1[3]=h[5]; r1[4]=l[0]; r1[5]=l[1]; r1[6]=l[2]; r1[7]=l[3];
            r2[0]=l[4]; r2[1]=l[5]; r2[2]=l[0]; r2[3]=l[1]; r2[4]=l[2]; r2[5]=l[3]; r2[6]=l[4]; r2[7]=l[5];
            r3 = (s16x8){0,0,0,0,0,0,0,0};
            s16x8* row = (s16x8*)&sU[t * LDP];
            row[0] = r0; row[1] = r1; row[2] = r2; row[3] = r3;
            sw_[t] = w;
        }
        __syncthreads();

#pragma unroll
        for (int jt = 0; jt < JT; ++jt) {
            s16x8 bfr = *(const s16x8*)&sU[((jt * 16 + col) * LDP) + quad * 8];
            float wv = sw_[jt * 16 + col];
#pragma unroll
            for (int n = 0; n < NF; ++n) {
                f32x4 g = __builtin_amdgcn_mfma_f32_16x16x32_bf16(
                    afr[n], bfr, (f32x4){0.f, 0.f, 0.f, 0.f}, 0, 0, 0);
#pragma unroll
                for (int r = 0; r < 4; ++r)
                    sacc[n][r] = fmaf(wv, __builtin_amdgcn_exp2f(g[r]), sacc[n][r]);
            }
        }
    }

    // ---- reduce over 16 cols (j) and store s ----
#pragma unroll
    for (int n = 0; n < NF; ++n) {
#pragma unroll
        for (int r = 0; r < 4; ++r) {
            float v = sacc[n][r];
            v += __shfl_xor(v, 1, 64);
            v += __shfl_xor(v, 2, 64);
            v += __shfl_xor(v, 4, 64);
            v += __shfl_xor(v, 8, 64);
            sacc[n][r] = v;
        }
        if (col == 0) {
            int ig = sup * ROWS + (wave * NF + n) * 16 + quad * 4;
            float4 st = make_float4(sacc[n][0], sacc[n][1], sacc[n][2], sacc[n][3]);
            *(float4*)&sbuf[base + ig] = st;
        }
    }
}

// ===== topk: relu-finish + RADIX-SELECT on packed u64 key + gather =========
__global__ __launch_bounds__(256) void topk_kernel(
        const float* __restrict__ sbuf, const float* __restrict__ cw,
        const float* __restrict__ cp, const float* __restrict__ cc,
        float* __restrict__ dw, float* __restrict__ dp, float* __restrict__ dc,
        float* __restrict__ trp, float* __restrict__ aip,
        int N, int K, int L) {
    __shared__ unsigned long long skey[1280];
    __shared__ float swn[1280];
    __shared__ int hist[256];
    __shared__ int suff[256];
    __shared__ int sel[32];
    __shared__ int scnt;
    __shared__ unsigned long long sprefix;
    __shared__ int sneed, sdone;

    int blv = blockIdx.x;
    int b = blv / L, l = blv % L;
    size_t base = (size_t)blv * N;
    int t = threadIdx.x;

    for (int j = t; j < N; j += 256) {
        float s = sbuf[base + j];
        float denom = (fabsf(s) > 1e-6f) ? s : 1e-6f;
        float wn = cw[base + j] * (fmaxf(s, 0.f) / denom);
        swn[j] = wn;
        float c00 = cc[3 * (base + j)], c01 = cc[3 * (base + j) + 1],
              c11 = cc[3 * (base + j) + 2];
        float det = c00 * c11 - c01 * c01;
        float sc = fabsf(wn) * sqrtf(fmaxf(det, 1e-12f));
        unsigned int ub = __float_as_uint(sc) | 0x80000000u;
        skey[j] = ((unsigned long long)ub << 32) | (unsigned int)(~j);
    }
    if (t == 0) { scnt = 0; }
    __syncthreads();

    // ---- radix-select threshold Wlo such that #{key >= Wlo} == K ----
    unsigned long long prefix = 0;
    int need = K;
    unsigned long long Wlo = 0;
    for (int lvl = 7; lvl >= 0; --lvl) {
        hist[t] = 0;
        __syncthreads();
        int sh = lvl * 8;
        unsigned long long pmask = (lvl == 7) ? 0ull : (~0ull << (sh + 8));
        for (int j = t; j < N; j += 256) {
            unsigned long long k_ = skey[j];
            if ((k_ & pmask) == prefix)
                atomicAdd(&hist[(int)((k_ >> sh) & 255)], 1);
        }
        __syncthreads();
        suff[t] = hist[t];
        __syncthreads();
        // inclusive suffix scan: suff[d] = sum_{e>=d} hist[e]
        for (int off = 1; off < 256; off <<= 1) {
            int add = (t + off < 256) ? suff[t + off] : 0;
            __syncthreads();
            suff[t] += add;
            __syncthreads();
        }
        int snx = (t < 255) ? suff[t + 1] : 0;
        if (suff[t] >= need && snx < need) {      // exactly one thread matches
            sprefix = prefix | ((unsigned long long)t << sh);
            sneed = need - snx;                   // rank within boundary bin
            sdone = (suff[t] == need);
        }
        __syncthreads();
        prefix = sprefix;
        need = sneed;
        if (sdone) { Wlo = prefix; break; }
        __syncthreads();   // protect sprefix/sneed/sdone before next level writes
    }
    // keys unique -> loop always exits via sdone by lvl 0

    // ---- gather: exactly K keys >= Wlo ----
    for (int j = t; j < N; j += 256) {
        if (skey[j] >= Wlo) {
            int slot = atomicAdd(&scnt, 1);
            if (slot < 32) sel[slot] = j;
        }
    }
    __syncthreads();

    float tr_c = 0.f, ai_c = 0.f;
    if (t < K) {
        int idx = sel[t];
        size_t j = base + idx;
        int o = blv * K + t;
        float wn = swn[idx];
        float c00 = cc[3 * j], c01 = cc[3 * j + 1], c11 = cc[3 * j + 2];
        dw[o] = wn;
        dp[2 * o] = cp[2 * j]; dp[2 * o + 1] = cp[2 * j + 1];
        dc[3 * o] = c00; dc[3 * o + 1] = c01; dc[3 * o + 2] = c11;
        tr_c = 0.5f * (c00 + c11);
        float det = c00 * c11 - c01 * c01;
        ai_c = fabsf(wn * TWO_PI_F * sqrtf(fmaxf(det, 1e-12f)));
    }
    if (t < 64) {
        for (int off = 32; off > 0; off >>= 1) {
            tr_c += __shfl_down(tr_c, off, 64);
            ai_c += __shfl_down(ai_c, off, 64);
        }
        if (t == 0) { trp[l * B + b] = tr_c; aip[l * B + b] = ai_c; }
    }
}

// ==== final: per-(b,co) partials; last block does norm + BN + log_softmax ===
__global__ __launch_bounds__(256) void final_kernel(
        const float* __restrict__ sbuf, const float* __restrict__ cw,
        const float* __restrict__ cc,
        float* __restrict__ tbuf, float* __restrict__ ubuf, float* __restrict__ abuf,
        int* __restrict__ cnt, float* __restrict__ out,
        int L, int N) {
    int blv = blockIdx.x;
    size_t base = (size_t)blv * N;
    int t = threadIdx.x;
    __shared__ float r1[256], r2[256], r3[256];

    float tsum = 0.f, usum = 0.f, asum = 0.f;
    for (int n = t; n < N; n += 256) {
        size_t o = base + n;
        float c00 = cc[3 * o], c01 = cc[3 * o + 1], c11 = cc[3 * o + 2];
        tsum += 0.5f * (c00 + c11);
        float s = sbuf[o];
        float denom = (fabsf(s) > 1e-6f) ? s : 1e-6f;
        float wn = cw[o] * (fmaxf(s, 0.f) / denom);
        float det = fmaxf(c00 * c11 - c01 * c01, 1e-30f);
        float integ = wn * TWO_PI_F * sqrtf(det);
        usum += integ;
        asum += fabsf(integ);
    }
    r1[t] = tsum; r2[t] = usum; r3[t] = asum;
    __syncthreads();
    for (int s = 128; s > 0; s >>= 1) {
        if (t < s) { r1[t] += r1[t + s]; r2[t] += r2[t + s]; r3[t] += r3[t + s]; }
        __syncthreads();
    }
    __shared__ int lastf;
    if (t == 0) {
        tbuf[blv] = r1[0]; ubuf[blv] = r2[0]; abuf[blv] = r3[0];
        __threadfence();
        lastf = (atomicAdd(cnt, 1) == (int)gridDim.x - 1);
    }
    __syncthreads();
    if (!lastf) return;
    __threadfence();

    __shared__ float xs[80];
    __shared__ float xn[80];
    if (t < L) {
        float tr = 0.f, a = 0.f;
        for (int bb = 0; bb < B; ++bb) { tr += tbuf[bb * L + t]; a += abuf[bb * L + t]; }
        float m = tr / (float)(B * N);
        float f = rsqrtf(m + 1e-8f);
        float f2 = f * f;
        float scale = f2 * a / (float)(B * N) + 1e-6f;
        for (int bb = 0; bb < B; ++bb) xs[bb * L + t] = f2 * ubuf[bb * L + t] / scale;
    }
    __syncthreads();
    if (t < L) {
        float mu = 0.f;
        for (int bb = 0; bb < B; ++bb) mu += xs[bb * L + t];
        mu *= 0.125f;
        float var = 0.f;
        for (int bb = 0; bb < B; ++bb) { float d = xs[bb * L + t] - mu; var += d * d; }
        var *= 0.125f;
        float inv = rsqrtf(var + 1e-5f);
        for (int bb = 0; bb < B; ++bb) xn[bb * L + t] = (xs[bb * L + t] - mu) * inv;
    }
    __syncthreads();
    if (t < B) {
        float mx = -INFINITY;
        for (int c = 0; c < L; ++c) mx = fmaxf(mx, xn[t * L + c]);
        float se = 0.f;
        for (int c = 0; c < L; ++c) se += expf(xn[t * L + c] - mx);
        float lse = mx + logf(se);
        for (int c = 0; c < L; ++c) out[t * L + c] = xn[t * L + c] - lse;
    }
}

extern "C" void kernel_launch(void* const* d_in, const int* in_sizes, int n_in,
                              void* d_out, int out_size, void* d_ws, size_t ws_size,
                              hipStream_t stream) {
    const float* in_w = (const float*)d_in[0];
    const float* in_p = (const float*)d_in[1];
    const float* in_c = (const float*)d_in[2];
    const float* kw[3] = {(const float*)d_in[3], (const float*)d_in[6], (const float*)d_in[9]};
    const float* kp[3] = {(const float*)d_in[4], (const float*)d_in[7], (const float*)d_in[10]};
    const float* kc[3] = {(const float*)d_in[5], (const float*)d_in[8], (const float*)d_in[11]};

    float* ws  = (float*)d_ws;
    float* dw  = ws + OFF_DW;
    float* dp  = ws + OFF_DP;
    float* dc  = ws + OFF_DC;
    float* cw  = ws + OFF_CW;
    float* cp  = ws + OFF_CP;
    float* cc  = ws + OFF_CC;
    float* sb  = ws + OFF_S;
    float* out = (float*)d_out;

    float* tail = ws + OFF_T;
    float* trp0 = tail;          // 64
    float* aip0 = tail + 64;     // 64
    float* trp1 = tail + 128;    // 128
    float* aip1 = tail + 256;    // 128
    float* tbuf = tail + 384;    // 80
    float* ubuf = tail + 464;    // 80
    float* abuf = tail + 544;    // 80
    int*   cnt  = (int*)(tail + 624);

    // layer 0: Co=8, Ci=1, Nd=128, N=640, ROWS=64 (NSUP=10 -> 640 blocks), JCH=128
    eval_mfma_kernel<8, 1, 128, true, 64, 128><<<8 * 8 * 10, 256, 0, stream>>>(
        in_w, in_p, in_c, kw[0], kp[0], kc[0], nullptr, nullptr,
        cw, cp, cc, sb, cnt);
    topk_kernel<<<64, 256, 0, stream>>>(sb, cw, cp, cc, dw, dp, dc,
                                        trp0, aip0, 640, 32, 8);
    // layer 1: Co=16, Ci=8, Nd=32, N=1280, ROWS=128, JCH=256 (NCH=5)
    eval_mfma_kernel<16, 8, 32, false, 128, 256><<<8 * 16 * 10, 256, 0, stream>>>(
        dw, dp, dc, kw[1], kp[1], kc[1], trp0, aip0, cw, cp, cc, sb, cnt);
    topk_kernel<<<128, 256, 0, stream>>>(sb, cw, cp, cc, dw, dp, dc,
                                         trp1, aip1, 1280, 16, 16);
    // layer 2: Co=10, Ci=16, Nd=16, N=1280, ROWS=128 (NSUP=10 -> 800 blocks), JCH=256
    eval_mfma_kernel<10, 16, 16, false, 128, 256><<<8 * 10 * 10, 256, 0, stream>>>(
        dw, dp, dc, kw[2], kp[2], kc[2], trp1, aip1, cw, cp, cc, sb, cnt);
    final_kernel<<<80, 256, 0, stream>>>(sb, cw, cc, tbuf, ubuf, abuf,
                                         cnt, out, 10, 1280);
}